// Round 11
// baseline (303.347 us; speedup 1.0000x reference)
//
#include <hip/hip_runtime.h>
#include <math.h>

// RegionProposalNetwork on MI355X (gfx950).
// Round 11: conv1_mfma rebuilt -- bf16 conversion moved to staging (7.5x fewer
// f2bf), cooperative im2col bf16 tile in LDS, MFMA loop is pure ds_read_b128
// (round 10 counters: 51us, VALUBusy 47%, 3.9M bank conflicts from per-lane
// scalar fragment build). Bit-identical arithmetic -> absmax stays 1168.

#define CAP 4096

typedef __attribute__((ext_vector_type(8))) short bf16x8;
typedef __attribute__((ext_vector_type(4))) float f32x4;

// ---------------- workspace layout (float offsets) ----------------
#define OFF_F1T     0          // 5,171,328 f = 402*402*64 bf16 (conv1 out, padded transposed)
#define OFF_HBUF    0          //  2,560,000 f (rpn hidden; overlays F1T which is dead by then)
#define OFF_FMT     5171328    // 1,331,712 f = 102*102*256 bf16 (fm, padded transposed)
#define OFF_CPART   6503040    //   720,000 (4*18*10000)
#define OFF_RPART   7223040    // 1,440,000 (4*36*10000)
#define OFF_WA1     8663040    //     5,120 f = 64*160 bf16 (conv1 weights, K-padded)
#define OFF_W9_2    8672448    //    73,728 f = 9*256*64 bf16   [kk][oc][ic]
#define OFF_W9_3    8746176    //   294,912 f = 36*256*64 bf16  [kk*4+ch][oc][icl]
#define OFF_WTC     9041088    //     4,608 [256][18] f32
#define OFF_WTG     9045696    //     9,216 [256][36] f32
#define OFF_AARG    9054912    //    90,000 (int)
#define OFF_NEGM    9144912    //     2,816 f = 1408 uint64 (neg label bitmask)
#define OFF_POSM    9147728    //     2,816 f = 1408 uint64 (pos label bitmask)
#define OFF_GTMAX   9150544    //    64 uint + counter (pad 80)
#define OFF_CANDS   9150688    //    4,096
#define OFF_CANDI   9154784    //    4,096 (int)

__device__ __forceinline__ unsigned short f2bf(float f) {   // RNE f32->bf16
    unsigned int u = __float_as_uint(f);
    u += 0x7fffu + ((u >> 16) & 1u);
    return (unsigned short)(u >> 16);
}

// ---------------- selection-path exact math ----------------
__device__ __forceinline__ void anchor_box(int i, float& x0, float& y0,
                                           float& x1, float& y1, float& area) {
#pragma clang fp contract(off)
    const float sizes[3]  = {128.f, 256.f, 512.f};
    const float ratios[3] = {0.5f, 1.f, 2.f};
    int a = i % 9;
    int q = i / 9;
    int iy = q % 100;
    int ix = q / 100;
    int s = a / 3, r = a % 3;
    float sq = sqrtf(ratios[r]);
    float w = sizes[s] * sq;
    float h = sizes[s] / sq;
    float cx = ((float)ix + 0.5f) * 16.0f;
    float cy = ((float)iy + 0.5f) * 16.0f;
    x0 = cx - w * 0.5f;
    y0 = cy - h * 0.5f;
    x1 = x0 + w;
    y1 = y0 + h;
    area = (x1 - x0) * (y1 - y0);
}

__device__ __forceinline__ float iou_one(float ax0, float ay0, float ax1, float ay1, float aa,
                                         float bx0, float by0, float bx1, float by1, float ab) {
#pragma clang fp contract(off)
    float ltx = fmaxf(ax0, bx0), lty = fmaxf(ay0, by0);
    float rbx = fminf(ax1, bx1), rby = fminf(ay1, by1);
    float iw = fmaxf(rbx - ltx, 0.0f);
    float ih = fmaxf(rby - lty, 0.0f);
    float inter = iw * ih;
    return inter / ((aa + ab) - inter);
}

// ---------------- merged setup: zero counters, pad borders, repack weights ----------------
__global__ __launch_bounds__(256) void setup_kernel(const float* __restrict__ wc, float* __restrict__ wtc,
                                                    const float* __restrict__ wg, float* __restrict__ wtg,
                                                    const float* __restrict__ w1, unsigned short* __restrict__ wa1,
                                                    const float* __restrict__ w2, unsigned short* __restrict__ w9_2,
                                                    const float* __restrict__ wr, unsigned short* __restrict__ w9_3,
                                                    unsigned int* __restrict__ f1t_u, unsigned int* __restrict__ fmt_u,
                                                    unsigned int* __restrict__ gtmax) {
    int i = blockIdx.x * 256 + threadIdx.x;
    if (i < 65) { gtmax[i] = 0u; return; }
    i -= 65;
    if (i < 103040) {   // zero pad borders of f1t / fmt
        if (i < 51328) {
            int p = i >> 5, part = i & 31;
            int x, y;
            if (p < 804) { y = (p < 402) ? 0 : 401; x = p % 402; }
            else { int j = p - 804; x = (j < 400) ? 0 : 401; y = 1 + (j % 400); }
            f1t_u[(y * 402 + x) * 32 + part] = 0u;
        } else {
            int i2 = i - 51328;
            int p = i2 >> 7, part = i2 & 127;
            int x, y;
            if (p < 204) { y = (p < 102) ? 0 : 101; x = p % 102; }
            else { int j = p - 204; x = (j < 100) ? 0 : 101; y = 1 + (j % 100); }
            fmt_u[(y * 102 + x) * 128 + part] = 0u;
        }
        return;
    }
    i -= 103040;
    if (i < 4608) { int c = i / 256, k = i - c * 256; wtc[k * 18 + c] = wc[i]; return; }
    i -= 4608;
    if (i < 9216) { int c = i / 256, k = i - c * 256; wtg[k * 36 + c] = wg[i]; return; }
    i -= 9216;
    if (i < 10240) {
        int oc = i / 160, k = i - oc * 160;
        wa1[i] = (k < 147) ? f2bf(w1[oc * 147 + k]) : (unsigned short)0;
        return;
    }
    i -= 10240;
    if (i < 147456) {   // conv2: [kk][oc][ic]
        int kk = i / 16384; int rem = i - kk * 16384;
        int oc = rem / 64, ic = rem - oc * 64;
        w9_2[i] = f2bf(w2[(oc * 64 + ic) * 9 + kk]);
        return;
    }
    i -= 147456;
    if (i < 589824) {   // conv3: [kk*4+ch][oc][icl], chunk-major
        int cc = i / 16384; int rem = i - cc * 16384;
        int oc = rem / 64, icl = rem - oc * 64;
        int kk = cc / 4, ch = cc - kk * 4;
        w9_3[i] = f2bf(wr[(oc * 256 + ch * 64 + icl) * 9 + kk]);
    }
}

// ---------------- conv1 via MFMA: 3->64, 7x7, s4, p3, im2col in LDS ----------------
// Block 256 thr, tile = 64 oc x 64 px (one output row). Window converted to bf16
// at staging; cooperative im2col build; MFMA loop = 20 ds_read_b128 + 20 MFMA.
__global__ __launch_bounds__(256) void conv1_mfma(const float* __restrict__ img,
                                                  const unsigned short* __restrict__ wA, // [64][160]
                                                  const float* __restrict__ bias,
                                                  unsigned short* __restrict__ f1t) {
    // smem: [0,5464) bf16 window [ic][ky][260] (dead after im2col build; reused as tileT)
    //       [5464,...) im2col [px][168] bf16 (rows 336B: 16B-aligned, 2-way banks = free)
    __shared__ unsigned short smem[5464 + 64 * 168];
    unsigned short* win   = smem;
    unsigned short* imcol = smem + 5464;
    unsigned short* tileT = smem;          // overlays win (row 72 shorts)
    int t = threadIdx.x;
    int wave = t >> 6, lane = t & 63;
    int quad = lane >> 4, l16 = lane & 15;
    int oy = blockIdx.y;
    int ox0 = blockIdx.x * 64;
    int gx0 = ox0 * 4 - 3;
    int gy0 = 4 * oy - 3;
    // stage window as bf16 (same f32 -> same RNE -> bit-identical to round 10)
    for (int idx = t; idx < 3 * 7 * 259; idx += 256) {
        int ic = idx / (7 * 259);
        int r = idx - ic * 7 * 259;
        int ky = r / 259, c = r - ky * 259;
        int gy = gy0 + ky, gx = gx0 + c;
        float v = 0.f;
        if (gy >= 0 && gy < 1600 && gx >= 0 && gx < 1600)
            v = img[(ic * 1600 + gy) * 1600 + gx];
        win[(ic * 7 + ky) * 260 + c] = f2bf(v);
    }
    bf16x8 afr[5];
    {
        const bf16x8* ap = (const bf16x8*)(wA + (wave * 16 + l16) * 160 + quad * 8);
#pragma unroll
        for (int c = 0; c < 5; c++) afr[c] = ap[c * 4];
    }
    __syncthreads();
    // cooperative im2col: imcol[px][k], k in [0,160), zeros for k >= 147
    for (int e = t; e < 64 * 160; e += 256) {
        int px = e / 160, k = e - px * 160;
        unsigned short v = 0;
        if (k < 147) {
            int ic = (k * 335) >> 14;          // k/49 for k<160
            int r = k - ic * 49;
            int ky = (r * 37) >> 8;            // r/7 for r<49
            int kx = r - ky * 7;
            v = win[(ic * 7 + ky) * 260 + 4 * px + kx];
        }
        imcol[px * 168 + k] = v;
    }
    __syncthreads();                            // win dead from here (tileT may overlay)

    f32x4 acc[4];
#pragma unroll
    for (int j = 0; j < 4; j++) acc[j] = (f32x4){0.f, 0.f, 0.f, 0.f};
#pragma unroll
    for (int ch = 0; ch < 5; ch++) {
#pragma unroll
        for (int j = 0; j < 4; j++) {
            bf16x8 b = *(const bf16x8*)(imcol + (j * 16 + l16) * 168 + ch * 32 + quad * 8);
            acc[j] = __builtin_amdgcn_mfma_f32_16x16x32_bf16(afr[ch], b, acc[j], 0, 0, 0);
        }
    }
#pragma unroll
    for (int reg = 0; reg < 4; reg++) {
        int oc = wave * 16 + quad * 4 + reg;
        float bv = bias[oc];
#pragma unroll
        for (int j = 0; j < 4; j++) {
            int px = j * 16 + l16;
            tileT[px * 72 + oc] = f2bf(fmaxf(acc[j][reg] + bv, 0.f));
        }
    }
    __syncthreads();
    int px = t >> 2, part = t & 3;
    int ox = ox0 + px;
    if (ox < 400) {
        int row = (oy + 1) * 402 + ox + 1;
        uint4 v = *(const uint4*)(tileT + px * 72 + part * 16);
        *(uint4*)(f1t + row * 64 + part * 16) = v;
    }
}

// ---------------- implicit-GEMM conv via MFMA bf16, double-LDS (m97 pattern) ----------------
template<int ICC, int RS, int S, bool WRT>
__global__ __launch_bounds__(256, 2) void conv_gemm(const unsigned short* __restrict__ Bt,
                                                    const unsigned short* __restrict__ A9, // [9*NC][256][64]
                                                    const float* __restrict__ bias,
                                                    float* __restrict__ outF,
                                                    unsigned short* __restrict__ outT) {
    const int NC = ICC / 64;
    const int HC = S * 24 + 3;          // halo cols: conv2=99, conv3=27
    const int LROW = ICC + 8;           // +16B pad
    __shared__ unsigned short blds[3 * HC * LROW];   // 42,768 B (both instantiations)
    __shared__ unsigned short alds[256 * 72];        // 36,864 B, row pad 72
    int t = threadIdx.x;
    int xs = blockIdx.x, y = blockIdx.y;

    const int CHW = ICC / 8;            // uint4 chunks per pixel-row
    for (int idx = t; idx < 3 * HC * CHW; idx += 256) {
        int row = idx / CHW, e = idx - row * CHW;
        int ky = row / HC, c = row - ky * HC;
        const uint4* src = (const uint4*)(Bt + ((size_t)(S * y + ky) * RS + S * xs * 25 + c) * ICC) + e;
        *(uint4*)(blds + row * LROW + e * 8) = *src;
    }
    int wave = t >> 6, lane = t & 63;
    int quad = lane >> 4, l16 = lane & 15;
    int oc0 = wave * 64;
    int pxe0 = min(l16, 24);
    int pxe1 = min(16 + l16, 24);

    f32x4 acc[4][2];
#pragma unroll
    for (int mt = 0; mt < 4; mt++)
#pragma unroll
        for (int j = 0; j < 2; j++) acc[mt][j] = (f32x4){0.f, 0.f, 0.f, 0.f};

    const unsigned short* a0 = alds + (oc0 + l16) * 72 + quad * 8;
    for (int cc = 0; cc < 9 * NC; cc++) {
        int pass = cc / NC, ch = cc - pass * NC;
        int ky = pass / 3, kx = pass - (pass / 3) * 3;
        __syncthreads();
        const uint4* asrc = (const uint4*)(A9 + (size_t)cc * 16384);
#pragma unroll
        for (int i = 0; i < 8; i++) {
            int e = i * 256 + t;
            *(uint4*)(alds + (e >> 3) * 72 + (e & 7) * 8) = asrc[e];
        }
        __syncthreads();
        const unsigned short* b0 = blds + (ky * HC + S * pxe0 + kx) * LROW + ch * 64 + quad * 8;
        const unsigned short* b1 = blds + (ky * HC + S * pxe1 + kx) * LROW + ch * 64 + quad * 8;
#pragma unroll
        for (int kcl = 0; kcl < 2; kcl++) {
            bf16x8 bf0 = *(const bf16x8*)(b0 + kcl * 32);
            bf16x8 bf1 = *(const bf16x8*)(b1 + kcl * 32);
#pragma unroll
            for (int mt = 0; mt < 4; mt++) {
                bf16x8 af = *(const bf16x8*)(a0 + mt * 16 * 72 + kcl * 32);
                acc[mt][0] = __builtin_amdgcn_mfma_f32_16x16x32_bf16(af, bf0, acc[mt][0], 0, 0, 0);
                acc[mt][1] = __builtin_amdgcn_mfma_f32_16x16x32_bf16(af, bf1, acc[mt][1], 0, 0, 0);
            }
        }
    }
#pragma unroll
    for (int mt = 0; mt < 4; mt++) {
#pragma unroll
        for (int reg = 0; reg < 4; reg++) {
            int oc = oc0 + mt * 16 + quad * 4 + reg;
            float bv = bias[oc];
#pragma unroll
            for (int j = 0; j < 2; j++) {
                int pl = j * 16 + l16;
                if (pl < 25) {
                    int p = y * 100 + xs * 25 + pl;
                    float v = fmaxf(acc[mt][j][reg] + bv, 0.f);
                    outF[oc * 10000 + p] = v;
                    if (WRT) {
                        int r = (y + 1) * 102 + xs * 25 + pl + 1;
                        outT[r * 256 + oc] = f2bf(v);
                    }
                }
            }
        }
    }
}

// ---------------- 1x1 heads: partial sums over 64-channel chunks ----------------
__global__ __launch_bounds__(64) void head_kernel(const float* __restrict__ hbuf,
                                                  const float* __restrict__ wtc,  // [256][18]
                                                  const float* __restrict__ wtg,  // [256][36]
                                                  float* __restrict__ cpart,      // [4][18][10000]
                                                  float* __restrict__ rpart) {    // [4][36][10000]
    int p = blockIdx.x * 64 + threadIdx.x;
    int ch = blockIdx.y;
    int ic0 = ch * 64;
    if (p >= 10000) return;
    float acc[54];
#pragma unroll
    for (int j = 0; j < 54; j++) acc[j] = 0.f;
    for (int ic = 0; ic < 64; ic++) {
        float v = hbuf[(ic0 + ic) * 10000 + p];
        const float* wc_ = wtc + (ic0 + ic) * 18;
#pragma unroll
        for (int j = 0; j < 18; j++) acc[j] += v * wc_[j];
        const float* wg_ = wtg + (ic0 + ic) * 36;
#pragma unroll
        for (int j = 0; j < 36; j++) acc[18 + j] += v * wg_[j];
    }
    for (int j = 0; j < 18; j++) cpart[(ch * 18 + j) * 10000 + p] = acc[j];
    for (int j = 0; j < 36; j++) rpart[(ch * 36 + j) * 10000 + p] = acc[18 + j];
}

// ---------------- IoU pass 1: anc argmax + per-gt max ----------------
__global__ __launch_bounds__(256) void iou_pass1(const float* __restrict__ gt,
                                                 int* __restrict__ aarg,
                                                 unsigned int* __restrict__ gtmax) {
    __shared__ float sg[64][4];
    __shared__ float sarea[64];
    __shared__ unsigned int smax[64];
    int t = threadIdx.x;
    if (t < 64) {
#pragma clang fp contract(off)
        float b0 = gt[t * 4 + 0], b1 = gt[t * 4 + 1];
        float b2 = gt[t * 4 + 2], b3 = gt[t * 4 + 3];
        sg[t][0] = b0; sg[t][1] = b1; sg[t][2] = b2; sg[t][3] = b3;
        sarea[t] = (b2 - b0) * (b3 - b1);
        smax[t] = 0u;
    }
    __syncthreads();
    int i = blockIdx.x * 256 + t;
    int iq = min(i, 89999);
    float x0, y0, x1, y1, aa;
    anchor_box(iq, x0, y0, x1, y1, aa);
    float best = -1.f;
    int bestj = 0;
    for (int j = 0; j < 64; j++) {
        float v = iou_one(x0, y0, x1, y1, aa, sg[j][0], sg[j][1], sg[j][2], sg[j][3], sarea[j]);
        if (v > best) { best = v; bestj = j; }
        float vm = v;
#pragma unroll
        for (int off = 32; off > 0; off >>= 1) vm = fmaxf(vm, __shfl_xor(vm, off));
        if ((t & 63) == 0) atomicMax(&smax[j], __float_as_uint(vm));
    }
    if (i < 90000) aarg[i] = bestj;
    __syncthreads();
    if (t < 64) atomicMax(&gtmax[t], smax[t]);
}

// ---------------- IoU pass 2: labels -> ballot masks + pos compaction ----------------
__global__ __launch_bounds__(256) void iou_pass2(const float* __restrict__ gt,
                                                 const unsigned int* __restrict__ gtmax,
                                                 unsigned long long* __restrict__ negmask,
                                                 unsigned long long* __restrict__ posmask,
                                                 float* __restrict__ cand_s,
                                                 int* __restrict__ cand_i,
                                                 unsigned int* __restrict__ cnt) {
    __shared__ float sg[64][4];
    __shared__ float sarea[64];
    __shared__ float sgm[64];
    int t = threadIdx.x;
    if (t < 64) {
#pragma clang fp contract(off)
        float b0 = gt[t * 4 + 0], b1 = gt[t * 4 + 1];
        float b2 = gt[t * 4 + 2], b3 = gt[t * 4 + 3];
        sg[t][0] = b0; sg[t][1] = b1; sg[t][2] = b2; sg[t][3] = b3;
        sarea[t] = (b2 - b0) * (b3 - b1);
        sgm[t] = __uint_as_float(gtmax[t]);
    }
    __syncthreads();
    int i = blockIdx.x * 256 + t;
    if (i >= 90000) return;
    float x0, y0, x1, y1, aa;
    anchor_box(i, x0, y0, x1, y1, aa);
    float best = -1.f;
    bool isbest = false;
    for (int j = 0; j < 64; j++) {
        float v = iou_one(x0, y0, x1, y1, aa, sg[j][0], sg[j][1], sg[j][2], sg[j][3], sarea[j]);
        if (v > best) best = v;
        if (v == sgm[j]) isbest = true;   // exact equality, identical f32 code path as pass 1
    }
    float label = -1.f;
    if (best < 0.2f) label = 0.f;
    if (isbest) label = 1.f;
    if (best > 0.7f) label = 1.f;
    unsigned long long negb = __ballot(label == 0.f);
    unsigned long long posb = __ballot(label == 1.f);
    if ((t & 63) == 0) { negmask[i >> 6] = negb; posmask[i >> 6] = posb; }
    if (label == 1.f) {
        unsigned int p = atomicAdd(cnt, 1u);
        if (p < CAP) { cand_s[p] = best; cand_i[p] = i; }
    }
}

// ---------------- single-wave helpers ----------------
__device__ __forceinline__ unsigned long long shflx64(unsigned long long v, int m) {
    int lo = __shfl_xor((int)(unsigned)(v & 0xFFFFFFFFull), m);
    int hi = __shfl_xor((int)(unsigned)(v >> 32), m);
    return ((unsigned long long)(unsigned)hi << 32) | (unsigned)lo;
}

// first-32 set bits (ascending index) of the 90000-bit mask; single wave, no barriers
__device__ int wave_first32(const unsigned long long* __restrict__ mask,
                            bool invert, int* __restrict__ outIdx, int lane) {
    const int NW = 1407;            // ceil(90000/64)
    const int WPT = 22;             // 64*22 = 1408 >= 1407
    unsigned long long mw[WPT];
    int cnt = 0;
#pragma unroll
    for (int u = 0; u < WPT; u++) {
        int w = lane * WPT + u;
        unsigned long long m = 0ull;
        if (w < NW) {
            m = mask[w];
            if (invert) m = ~m;
            if (w == NW - 1) m &= 0xFFFFull;    // anchors 89984..89999 only
        }
        mw[u] = m;
        cnt += __builtin_popcountll(m);
    }
    int inc = cnt;                  // inclusive prefix over lanes via shuffles
#pragma unroll
    for (int off = 1; off < 64; off <<= 1) {
        int v = __shfl_up(inc, off);
        if (lane >= off) inc += v;
    }
    int total = __shfl(inc, 63);
    int pref = inc - cnt;           // exclusive prefix
    if (pref < 32) {
#pragma unroll
        for (int u = 0; u < WPT; u++) {
            unsigned long long m = mw[u];
            int wbase = (lane * WPT + u) * 64;
            while (m && pref < 32) {
                int b = __builtin_ctzll(m);
                outIdx[pref++] = wbase + b;
                m &= m - 1;
            }
        }
    }
    return total;
}

// ---------------- tail: top-k selection + proposals + losses (one wave) ----------------
__global__ __launch_bounds__(64) void tail_kernel(const unsigned long long* __restrict__ negmask,
                                                  const unsigned long long* __restrict__ posmask,
                                                  const float* __restrict__ cand_s,
                                                  const int* __restrict__ cand_i,
                                                  const unsigned int* __restrict__ cnt,
                                                  const float* __restrict__ cpart,
                                                  const float* __restrict__ rpart,
                                                  const float* __restrict__ bcls,
                                                  const float* __restrict__ breg,
                                                  const int* __restrict__ aarg,
                                                  const float* __restrict__ gt,
                                                  const int* __restrict__ gtc,
                                                  float* __restrict__ out) {
    __shared__ unsigned long long keys[CAP + 32];
    __shared__ int sfill[32];
    __shared__ int spidx[32];
    __shared__ int snidx[32];
    int lane = threadIdx.x;

    // ---- build sort keys: (monotonic(score) << 32) | ~index  => max = (score desc, idx asc)
    int ncand = min((int)*cnt, CAP);
    for (int c = lane; c < ncand; c += 64) {
        unsigned u = __float_as_uint(cand_s[c]);
        u ^= (u & 0x80000000u) ? 0xFFFFFFFFu : 0x80000000u;
        keys[c] = ((unsigned long long)u << 32) | (0xFFFFFFFFu - (unsigned)cand_i[c]);
    }
    int ntot = ncand;
    if (ncand < 32) {               // jax top_k tie fill: first label!=1 anchors at value -1
        int tot = wave_first32(posmask, true, sfill, lane);
        int nfill = min(tot, 32);
        unsigned um1 = __float_as_uint(-1.0f) ^ 0xFFFFFFFFu;
        for (int k2 = lane; k2 < nfill; k2 += 64)
            keys[ncand + k2] = ((unsigned long long)um1 << 32) | (0xFFFFFFFFu - (unsigned)sfill[k2]);
        ntot += nfill;
    }

    // ---- 32 rounds of wave argmax; lane owns slots c == lane (mod 64) so a
    // removal never invalidates another lane's cached local max
    unsigned long long lk = 0ull; int ls = -1;
    for (int c = lane; c < ntot; c += 64) {
        unsigned long long k = keys[c];
        if (k > lk) { lk = k; ls = c; }
    }
    for (int s = 0; s < 32; s++) {
        unsigned long long mk = lk;
#pragma unroll
        for (int off = 1; off < 64; off <<= 1) {
            unsigned long long o = shflx64(mk, off);
            if (o > mk) mk = o;
        }
        if (lk == mk && mk != 0ull) {   // unique winner (keys embed unique indices)
            spidx[s] = (int)(0xFFFFFFFFu - (unsigned)(mk & 0xFFFFFFFFull));
            keys[ls] = 0ull;
            lk = 0ull; ls = -1;
            for (int c = lane; c < ntot; c += 64) {
                unsigned long long k = keys[c];
                if (k > lk) { lk = k; ls = c; }
            }
        }
    }

    // ---- negatives: first 32 label==0 anchors (ascending index)
    int totn = wave_first32(negmask, false, snidx, lane);
    if (lane == 0) {
        int nf = min(totn, 32);
        for (int s = nf; s < 32; s++) snidx[s] = s;   // degenerate fallback
    }

    // ---- finalize (same math as before) ----
    {
#pragma clang fp contract(off)
        const int PROP_OFF = 1 + 2560000;
        int t = lane;
        int n = (t < 32) ? spidx[t] : snidx[t - 32];
        int a = n % 9;
        int q = n / 9;
        int iy = q % 100;
        int ix = q / 100;
        int p = iy * 100 + ix;

        float l0 = bcls[a * 2 + 0], l1 = bcls[a * 2 + 1];
        for (int c = 0; c < 4; c++) {
            l0 += cpart[(c * 18 + a * 2 + 0) * 10000 + p];
            l1 += cpart[(c * 18 + a * 2 + 1) * 10000 + p];
        }
        float m = fmaxf(l0, l1);
        float lse = m + logf(expf(l0 - m) + expf(l1 - m));
        float logp = ((t < 32) ? l1 : l0) - lse;
        float cls_sum = logp;
#pragma unroll
        for (int off = 32; off > 0; off >>= 1) cls_sum += __shfl_down(cls_sum, off);

        float reg_sum = 0.f;
        if (t < 32) {
            float offv[4];
#pragma unroll
            for (int k = 0; k < 4; k++) {
                float v = breg[a * 4 + k];
                for (int c = 0; c < 4; c++) v += rpart[(c * 36 + a * 4 + k) * 10000 + p];
                offv[k] = v;
            }
            float x0, y0, x1, y1, aa;
            anchor_box(n, x0, y0, x1, y1, aa);
            float w = x1 - x0, h = y1 - y0;
            float cx = x0 + 0.5f * w, cy = y0 + 0.5f * h;
            float ncx = cx + offv[0] * w, ncy = cy + offv[1] * h;
            float nw = w * expf(offv[2]), nh = h * expf(offv[3]);
            out[PROP_OFF + t * 4 + 0] = ncx - nw * 0.5f;
            out[PROP_OFF + t * 4 + 1] = ncy - nh * 0.5f;
            out[PROP_OFF + t * 4 + 2] = ncx + nw * 0.5f;
            out[PROP_OFF + t * 4 + 3] = ncy + nh * 0.5f;

            int j = aarg[n];
            float g0 = gt[j * 4 + 0], g1 = gt[j * 4 + 1];
            float g2 = gt[j * 4 + 2], g3 = gt[j * 4 + 3];
            float gw = g2 - g0, gh = g3 - g1;
            float gcx = g0 + 0.5f * gw, gcy = g1 + 0.5f * gh;
            float tg[4];
            tg[0] = (gcx - cx) / w;
            tg[1] = (gcy - cy) / h;
            tg[2] = logf(gw / w);
            tg[3] = logf(gh / h);
#pragma unroll
            for (int k = 0; k < 4; k++) {
                float d = tg[k] - offv[k];
                float ad = fabsf(d);
                reg_sum += (ad < 1.f) ? 0.5f * d * d : ad - 0.5f;
            }
            out[PROP_OFF + 128 + t] = (float)n;
            out[PROP_OFF + 160 + t] = (float)gtc[j];
        }
#pragma unroll
        for (int off = 32; off > 0; off >>= 1) reg_sum += __shfl_down(reg_sum, off);
        if (t == 0) {
            float cls_loss = -(cls_sum / 64.f);
            float reg_loss = reg_sum / 128.f;
            out[0] = cls_loss + 5.f * reg_loss;
        }
    }
}

// ---------------- launch ----------------
extern "C" void kernel_launch(void* const* d_in, const int* in_sizes, int n_in,
                              void* d_out, int out_size, void* d_ws, size_t ws_size,
                              hipStream_t stream) {
    const float* img = (const float*)d_in[0];
    const float* gt  = (const float*)d_in[1];
    const int*   gtc = (const int*)d_in[2];
    const float* w1  = (const float*)d_in[3];
    const float* b1  = (const float*)d_in[4];
    const float* w2  = (const float*)d_in[5];
    const float* b2  = (const float*)d_in[6];
    const float* wr  = (const float*)d_in[7];
    const float* br  = (const float*)d_in[8];
    const float* wc  = (const float*)d_in[9];
    const float* bc  = (const float*)d_in[10];
    const float* wg  = (const float*)d_in[11];
    const float* bg  = (const float*)d_in[12];
    float* out = (float*)d_out;
    float* ws = (float*)d_ws;

    unsigned short* f1t  = (unsigned short*)(ws + OFF_F1T);
    unsigned short* fmt  = (unsigned short*)(ws + OFF_FMT);
    unsigned short* wa1  = (unsigned short*)(ws + OFF_WA1);
    unsigned short* w9_2 = (unsigned short*)(ws + OFF_W9_2);
    unsigned short* w9_3 = (unsigned short*)(ws + OFF_W9_3);
    float* hbuf  = ws + OFF_HBUF;
    float* cpart = ws + OFF_CPART;
    float* rpart = ws + OFF_RPART;
    float* wtc   = ws + OFF_WTC;
    float* wtg   = ws + OFF_WTG;
    int*   aarg  = (int*)(ws + OFF_AARG);
    unsigned long long* negm = (unsigned long long*)(ws + OFF_NEGM);
    unsigned long long* posm = (unsigned long long*)(ws + OFF_POSM);
    unsigned int* gtmax = (unsigned int*)(ws + OFF_GTMAX);
    unsigned int* cnt   = gtmax + 64;
    float* cands = ws + OFF_CANDS;
    int*   candi = (int*)(ws + OFF_CANDI);
    float* fm    = out + 1;   // fm lives directly in the output buffer (f32)

    setup_kernel<<<dim3(3377), dim3(256), 0, stream>>>(wc, wtc, wg, wtg, w1, wa1,
                                                       w2, w9_2, wr, w9_3,
                                                       (unsigned int*)f1t, (unsigned int*)fmt, gtmax);

    conv1_mfma<<<dim3(7, 400), dim3(256), 0, stream>>>(img, wa1, b1, f1t);
    conv_gemm<64, 402, 4, true><<<dim3(4, 100), dim3(256), 0, stream>>>(f1t, w9_2, b2, fm, fmt);
    conv_gemm<256, 102, 1, false><<<dim3(4, 100), dim3(256), 0, stream>>>(fmt, w9_3, br, hbuf, nullptr);
    head_kernel<<<dim3(157, 4), dim3(64), 0, stream>>>(hbuf, wtc, wtg, cpart, rpart);

    iou_pass1<<<dim3(352), dim3(256), 0, stream>>>(gt, aarg, gtmax);
    iou_pass2<<<dim3(352), dim3(256), 0, stream>>>(gt, gtmax, negm, posm, cands, candi, cnt);
    tail_kernel<<<dim3(1), dim3(64), 0, stream>>>(negm, posm, cands, candi, cnt,
                                                  cpart, rpart, bc, bg, aarg, gt, gtc, out);
}

// Round 12
// 294.349 us; speedup vs baseline: 1.0306x; 1.0306x over previous
//
#include <hip/hip_runtime.h>
#include <math.h>

// RegionProposalNetwork on MI355X (gfx950).
// Round 12: conv1 K reordered to (ky*3+ic)*8+kx (K=192) so the MFMA B-fragment
// is a direct 2x ds_read_b64 from the staged window -- no im2col, no per-element
// decode. FIXED the round-4 f1t epilogue bug (only half of each 64-short row
// was written; other half read as ~0 -> the absmax=1168). absmax should drop
// to bf16 level. Everything else unchanged from round 11.

#define CAP 4096

typedef __attribute__((ext_vector_type(8))) short bf16x8;
typedef __attribute__((ext_vector_type(4))) float f32x4;

// ---------------- workspace layout (float offsets) ----------------
#define OFF_F1T     0          // 5,171,328 f = 402*402*64 bf16 (conv1 out, padded transposed)
#define OFF_HBUF    0          //  2,560,000 f (rpn hidden; overlays F1T which is dead by then)
#define OFF_FMT     5171328    // 1,331,712 f = 102*102*256 bf16 (fm, padded transposed)
#define OFF_CPART   6503040    //   720,000 (4*18*10000)
#define OFF_RPART   7223040    // 1,440,000 (4*36*10000)
#define OFF_WA1     8663040    //     6,144 f = 64*192 bf16 (conv1 weights, K'=192)
#define OFF_W9_2    8672448    //    73,728 f = 9*256*64 bf16   [kk][oc][ic]
#define OFF_W9_3    8746176    //   294,912 f = 36*256*64 bf16  [kk*4+ch][oc][icl]
#define OFF_WTC     9041088    //     4,608 [256][18] f32
#define OFF_WTG     9045696    //     9,216 [256][36] f32
#define OFF_AARG    9054912    //    90,000 (int)
#define OFF_NEGM    9144912    //     2,816 f = 1408 uint64 (neg label bitmask)
#define OFF_POSM    9147728    //     2,816 f = 1408 uint64 (pos label bitmask)
#define OFF_GTMAX   9150544    //    64 uint + counter (pad 80)
#define OFF_CANDS   9150688    //    4,096
#define OFF_CANDI   9154784    //    4,096 (int)

__device__ __forceinline__ unsigned short f2bf(float f) {   // RNE f32->bf16
    unsigned int u = __float_as_uint(f);
    u += 0x7fffu + ((u >> 16) & 1u);
    return (unsigned short)(u >> 16);
}

// ---------------- selection-path exact math ----------------
__device__ __forceinline__ void anchor_box(int i, float& x0, float& y0,
                                           float& x1, float& y1, float& area) {
#pragma clang fp contract(off)
    const float sizes[3]  = {128.f, 256.f, 512.f};
    const float ratios[3] = {0.5f, 1.f, 2.f};
    int a = i % 9;
    int q = i / 9;
    int iy = q % 100;
    int ix = q / 100;
    int s = a / 3, r = a % 3;
    float sq = sqrtf(ratios[r]);
    float w = sizes[s] * sq;
    float h = sizes[s] / sq;
    float cx = ((float)ix + 0.5f) * 16.0f;
    float cy = ((float)iy + 0.5f) * 16.0f;
    x0 = cx - w * 0.5f;
    y0 = cy - h * 0.5f;
    x1 = x0 + w;
    y1 = y0 + h;
    area = (x1 - x0) * (y1 - y0);
}

__device__ __forceinline__ float iou_one(float ax0, float ay0, float ax1, float ay1, float aa,
                                         float bx0, float by0, float bx1, float by1, float ab) {
#pragma clang fp contract(off)
    float ltx = fmaxf(ax0, bx0), lty = fmaxf(ay0, by0);
    float rbx = fminf(ax1, bx1), rby = fminf(ay1, by1);
    float iw = fmaxf(rbx - ltx, 0.0f);
    float ih = fmaxf(rby - lty, 0.0f);
    float inter = iw * ih;
    return inter / ((aa + ab) - inter);
}

// ---------------- merged setup: zero counters, pad borders, repack weights ----------------
__global__ __launch_bounds__(256) void setup_kernel(const float* __restrict__ wc, float* __restrict__ wtc,
                                                    const float* __restrict__ wg, float* __restrict__ wtg,
                                                    const float* __restrict__ w1, unsigned short* __restrict__ wa1,
                                                    const float* __restrict__ w2, unsigned short* __restrict__ w9_2,
                                                    const float* __restrict__ wr, unsigned short* __restrict__ w9_3,
                                                    unsigned int* __restrict__ f1t_u, unsigned int* __restrict__ fmt_u,
                                                    unsigned int* __restrict__ gtmax) {
    int i = blockIdx.x * 256 + threadIdx.x;
    if (i < 65) { gtmax[i] = 0u; return; }
    i -= 65;
    if (i < 103040) {   // zero pad borders of f1t / fmt
        if (i < 51328) {
            int p = i >> 5, part = i & 31;
            int x, y;
            if (p < 804) { y = (p < 402) ? 0 : 401; x = p % 402; }
            else { int j = p - 804; x = (j < 400) ? 0 : 401; y = 1 + (j % 400); }
            f1t_u[(y * 402 + x) * 32 + part] = 0u;
        } else {
            int i2 = i - 51328;
            int p = i2 >> 7, part = i2 & 127;
            int x, y;
            if (p < 204) { y = (p < 102) ? 0 : 101; x = p % 102; }
            else { int j = p - 204; x = (j < 100) ? 0 : 101; y = 1 + (j % 100); }
            fmt_u[(y * 102 + x) * 128 + part] = 0u;
        }
        return;
    }
    i -= 103040;
    if (i < 4608) { int c = i / 256, k = i - c * 256; wtc[k * 18 + c] = wc[i]; return; }
    i -= 4608;
    if (i < 9216) { int c = i / 256, k = i - c * 256; wtg[k * 36 + c] = wg[i]; return; }
    i -= 9216;
    if (i < 12288) {    // conv1 weights -> [oc][k'], k' = (ky*3+ic)*8 + kx, K'=192
        int oc = i / 192, k = i - oc * 192;
        int q = k >> 3, kx = k & 7;
        int ky = q / 3, ic = q - (q / 3) * 3;
        wa1[i] = (q < 21 && kx < 7) ? f2bf(w1[oc * 147 + ic * 49 + ky * 7 + kx])
                                    : (unsigned short)0;
        return;
    }
    i -= 12288;
    if (i < 147456) {   // conv2: [kk][oc][ic]
        int kk = i / 16384; int rem = i - kk * 16384;
        int oc = rem / 64, ic = rem - oc * 64;
        w9_2[i] = f2bf(w2[(oc * 64 + ic) * 9 + kk]);
        return;
    }
    i -= 147456;
    if (i < 589824) {   // conv3: [kk*4+ch][oc][icl], chunk-major
        int cc = i / 16384; int rem = i - cc * 16384;
        int oc = rem / 64, icl = rem - oc * 64;
        int kk = cc / 4, ch = cc - kk * 4;
        w9_3[i] = f2bf(wr[(oc * 256 + ch * 64 + icl) * 9 + kk]);
    }
}

// ---------------- conv1 via MFMA: 3->64, 7x7, s4, p3 ----------------
// Window rows indexed p' = ky*3+ic (rows 21..23 zero). B-fragment for (ch,quad)
// = 8 consecutive shorts of row p'=ch*4+quad at col 4*px -> 2x ds_read_b64.
__global__ __launch_bounds__(256) void conv1_mfma(const float* __restrict__ img,
                                                  const unsigned short* __restrict__ wA, // [64][192]
                                                  const float* __restrict__ bias,
                                                  unsigned short* __restrict__ f1t) {
    __shared__ unsigned short win[24 * 260];    // 12,480 B
    __shared__ unsigned short tileT[64 * 72];   //  9,216 B
    int t = threadIdx.x;
    int wave = t >> 6, lane = t & 63;
    int quad = lane >> 4, l16 = lane & 15;
    int oy = blockIdx.y;
    int ox0 = blockIdx.x * 64;
    int gx0 = ox0 * 4 - 3;
    int gy0 = 4 * oy - 3;

    // stage window bf16, uniform-outer loop (no per-element divisions)
    for (int r = 0; r < 24; r++) {
        int ky = r / 3, ic = r - (r / 3) * 3;   // wave-uniform scalar
        int gy = gy0 + ky;
        bool rowok = (r < 21) && (gy >= 0) && (gy < 1600);
        {
            int gx = gx0 + t;
            float v = (rowok && gx >= 0 && gx < 1600) ? img[(ic * 1600 + gy) * 1600 + gx] : 0.f;
            win[r * 260 + t] = f2bf(v);
        }
        if (t < 4) {
            int c2 = 256 + t;
            int gx = gx0 + c2;
            float v = (rowok && gx >= 0 && gx < 1600) ? img[(ic * 1600 + gy) * 1600 + gx] : 0.f;
            win[r * 260 + c2] = f2bf(v);
        }
    }
    bf16x8 afr[6];
    {
        const bf16x8* ap = (const bf16x8*)(wA + (wave * 16 + l16) * 192 + quad * 8);
#pragma unroll
        for (int c = 0; c < 6; c++) afr[c] = ap[c * 4];
    }
    __syncthreads();

    f32x4 acc[4];
#pragma unroll
    for (int j = 0; j < 4; j++) acc[j] = (f32x4){0.f, 0.f, 0.f, 0.f};
#pragma unroll
    for (int ch = 0; ch < 6; ch++) {
        const unsigned short* wrow = win + (ch * 4 + quad) * 260;
#pragma unroll
        for (int j = 0; j < 4; j++) {
            int px = j * 16 + l16;
            const unsigned long long* bp = (const unsigned long long*)(wrow + 4 * px); // 8B-aligned
            union { unsigned long long u[2]; bf16x8 v; } uu;
            uu.u[0] = bp[0];
            uu.u[1] = bp[1];
            acc[j] = __builtin_amdgcn_mfma_f32_16x16x32_bf16(afr[ch], uu.v, acc[j], 0, 0, 0);
        }
    }
#pragma unroll
    for (int reg = 0; reg < 4; reg++) {
        int oc = wave * 16 + quad * 4 + reg;
        float bv = bias[oc];
#pragma unroll
        for (int j = 0; j < 4; j++) {
            int px = j * 16 + l16;
            tileT[px * 72 + oc] = f2bf(fmaxf(acc[j][reg] + bv, 0.f));
        }
    }
    __syncthreads();
    int px = t >> 2, part = t & 3;
    int ox = ox0 + px;
    if (ox < 400) {
        int row = (oy + 1) * 402 + ox + 1;
        uint4 v0 = *(const uint4*)(tileT + px * 72 + part * 16);
        uint4 v1 = *(const uint4*)(tileT + px * 72 + part * 16 + 8);
        *(uint4*)(f1t + row * 64 + part * 16) = v0;       // full 64-short row now
        *(uint4*)(f1t + row * 64 + part * 16 + 8) = v1;   // (round-4 bug wrote only half)
    }
}

// ---------------- implicit-GEMM conv via MFMA bf16, double-LDS (m97 pattern) ----------------
template<int ICC, int RS, int S, bool WRT>
__global__ __launch_bounds__(256, 2) void conv_gemm(const unsigned short* __restrict__ Bt,
                                                    const unsigned short* __restrict__ A9, // [9*NC][256][64]
                                                    const float* __restrict__ bias,
                                                    float* __restrict__ outF,
                                                    unsigned short* __restrict__ outT) {
    const int NC = ICC / 64;
    const int HC = S * 24 + 3;          // halo cols: conv2=99, conv3=27
    const int LROW = ICC + 8;           // +16B pad
    __shared__ unsigned short blds[3 * HC * LROW];   // 42,768 B (both instantiations)
    __shared__ unsigned short alds[256 * 72];        // 36,864 B, row pad 72
    int t = threadIdx.x;
    int xs = blockIdx.x, y = blockIdx.y;

    const int CHW = ICC / 8;            // uint4 chunks per pixel-row
    for (int idx = t; idx < 3 * HC * CHW; idx += 256) {
        int row = idx / CHW, e = idx - row * CHW;
        int ky = row / HC, c = row - ky * HC;
        const uint4* src = (const uint4*)(Bt + ((size_t)(S * y + ky) * RS + S * xs * 25 + c) * ICC) + e;
        *(uint4*)(blds + row * LROW + e * 8) = *src;
    }
    int wave = t >> 6, lane = t & 63;
    int quad = lane >> 4, l16 = lane & 15;
    int oc0 = wave * 64;
    int pxe0 = min(l16, 24);
    int pxe1 = min(16 + l16, 24);

    f32x4 acc[4][2];
#pragma unroll
    for (int mt = 0; mt < 4; mt++)
#pragma unroll
        for (int j = 0; j < 2; j++) acc[mt][j] = (f32x4){0.f, 0.f, 0.f, 0.f};

    const unsigned short* a0 = alds + (oc0 + l16) * 72 + quad * 8;
    for (int cc = 0; cc < 9 * NC; cc++) {
        int pass = cc / NC, ch = cc - pass * NC;
        int ky = pass / 3, kx = pass - (pass / 3) * 3;
        __syncthreads();
        const uint4* asrc = (const uint4*)(A9 + (size_t)cc * 16384);
#pragma unroll
        for (int i = 0; i < 8; i++) {
            int e = i * 256 + t;
            *(uint4*)(alds + (e >> 3) * 72 + (e & 7) * 8) = asrc[e];
        }
        __syncthreads();
        const unsigned short* b0 = blds + (ky * HC + S * pxe0 + kx) * LROW + ch * 64 + quad * 8;
        const unsigned short* b1 = blds + (ky * HC + S * pxe1 + kx) * LROW + ch * 64 + quad * 8;
#pragma unroll
        for (int kcl = 0; kcl < 2; kcl++) {
            bf16x8 bf0 = *(const bf16x8*)(b0 + kcl * 32);
            bf16x8 bf1 = *(const bf16x8*)(b1 + kcl * 32);
#pragma unroll
            for (int mt = 0; mt < 4; mt++) {
                bf16x8 af = *(const bf16x8*)(a0 + mt * 16 * 72 + kcl * 32);
                acc[mt][0] = __builtin_amdgcn_mfma_f32_16x16x32_bf16(af, bf0, acc[mt][0], 0, 0, 0);
                acc[mt][1] = __builtin_amdgcn_mfma_f32_16x16x32_bf16(af, bf1, acc[mt][1], 0, 0, 0);
            }
        }
    }
#pragma unroll
    for (int mt = 0; mt < 4; mt++) {
#pragma unroll
        for (int reg = 0; reg < 4; reg++) {
            int oc = oc0 + mt * 16 + quad * 4 + reg;
            float bv = bias[oc];
#pragma unroll
            for (int j = 0; j < 2; j++) {
                int pl = j * 16 + l16;
                if (pl < 25) {
                    int p = y * 100 + xs * 25 + pl;
                    float v = fmaxf(acc[mt][j][reg] + bv, 0.f);
                    outF[oc * 10000 + p] = v;
                    if (WRT) {
                        int r = (y + 1) * 102 + xs * 25 + pl + 1;
                        outT[r * 256 + oc] = f2bf(v);
                    }
                }
            }
        }
    }
}

// ---------------- 1x1 heads: partial sums over 64-channel chunks ----------------
__global__ __launch_bounds__(64) void head_kernel(const float* __restrict__ hbuf,
                                                  const float* __restrict__ wtc,  // [256][18]
                                                  const float* __restrict__ wtg,  // [256][36]
                                                  float* __restrict__ cpart,      // [4][18][10000]
                                                  float* __restrict__ rpart) {    // [4][36][10000]
    int p = blockIdx.x * 64 + threadIdx.x;
    int ch = blockIdx.y;
    int ic0 = ch * 64;
    if (p >= 10000) return;
    float acc[54];
#pragma unroll
    for (int j = 0; j < 54; j++) acc[j] = 0.f;
    for (int ic = 0; ic < 64; ic++) {
        float v = hbuf[(ic0 + ic) * 10000 + p];
        const float* wc_ = wtc + (ic0 + ic) * 18;
#pragma unroll
        for (int j = 0; j < 18; j++) acc[j] += v * wc_[j];
        const float* wg_ = wtg + (ic0 + ic) * 36;
#pragma unroll
        for (int j = 0; j < 36; j++) acc[18 + j] += v * wg_[j];
    }
    for (int j = 0; j < 18; j++) cpart[(ch * 18 + j) * 10000 + p] = acc[j];
    for (int j = 0; j < 36; j++) rpart[(ch * 36 + j) * 10000 + p] = acc[18 + j];
}

// ---------------- IoU pass 1: anc argmax + per-gt max ----------------
__global__ __launch_bounds__(256) void iou_pass1(const float* __restrict__ gt,
                                                 int* __restrict__ aarg,
                                                 unsigned int* __restrict__ gtmax) {
    __shared__ float sg[64][4];
    __shared__ float sarea[64];
    __shared__ unsigned int smax[64];
    int t = threadIdx.x;
    if (t < 64) {
#pragma clang fp contract(off)
        float b0 = gt[t * 4 + 0], b1 = gt[t * 4 + 1];
        float b2 = gt[t * 4 + 2], b3 = gt[t * 4 + 3];
        sg[t][0] = b0; sg[t][1] = b1; sg[t][2] = b2; sg[t][3] = b3;
        sarea[t] = (b2 - b0) * (b3 - b1);
        smax[t] = 0u;
    }
    __syncthreads();
    int i = blockIdx.x * 256 + t;
    int iq = min(i, 89999);
    float x0, y0, x1, y1, aa;
    anchor_box(iq, x0, y0, x1, y1, aa);
    float best = -1.f;
    int bestj = 0;
    for (int j = 0; j < 64; j++) {
        float v = iou_one(x0, y0, x1, y1, aa, sg[j][0], sg[j][1], sg[j][2], sg[j][3], sarea[j]);
        if (v > best) { best = v; bestj = j; }
        float vm = v;
#pragma unroll
        for (int off = 32; off > 0; off >>= 1) vm = fmaxf(vm, __shfl_xor(vm, off));
        if ((t & 63) == 0) atomicMax(&smax[j], __float_as_uint(vm));
    }
    if (i < 90000) aarg[i] = bestj;
    __syncthreads();
    if (t < 64) atomicMax(&gtmax[t], smax[t]);
}

// ---------------- IoU pass 2: labels -> ballot masks + pos compaction ----------------
__global__ __launch_bounds__(256) void iou_pass2(const float* __restrict__ gt,
                                                 const unsigned int* __restrict__ gtmax,
                                                 unsigned long long* __restrict__ negmask,
                                                 unsigned long long* __restrict__ posmask,
                                                 float* __restrict__ cand_s,
                                                 int* __restrict__ cand_i,
                                                 unsigned int* __restrict__ cnt) {
    __shared__ float sg[64][4];
    __shared__ float sarea[64];
    __shared__ float sgm[64];
    int t = threadIdx.x;
    if (t < 64) {
#pragma clang fp contract(off)
        float b0 = gt[t * 4 + 0], b1 = gt[t * 4 + 1];
        float b2 = gt[t * 4 + 2], b3 = gt[t * 4 + 3];
        sg[t][0] = b0; sg[t][1] = b1; sg[t][2] = b2; sg[t][3] = b3;
        sarea[t] = (b2 - b0) * (b3 - b1);
        sgm[t] = __uint_as_float(gtmax[t]);
    }
    __syncthreads();
    int i = blockIdx.x * 256 + t;
    if (i >= 90000) return;
    float x0, y0, x1, y1, aa;
    anchor_box(i, x0, y0, x1, y1, aa);
    float best = -1.f;
    bool isbest = false;
    for (int j = 0; j < 64; j++) {
        float v = iou_one(x0, y0, x1, y1, aa, sg[j][0], sg[j][1], sg[j][2], sg[j][3], sarea[j]);
        if (v > best) best = v;
        if (v == sgm[j]) isbest = true;   // exact equality, identical f32 code path as pass 1
    }
    float label = -1.f;
    if (best < 0.2f) label = 0.f;
    if (isbest) label = 1.f;
    if (best > 0.7f) label = 1.f;
    unsigned long long negb = __ballot(label == 0.f);
    unsigned long long posb = __ballot(label == 1.f);
    if ((t & 63) == 0) { negmask[i >> 6] = negb; posmask[i >> 6] = posb; }
    if (label == 1.f) {
        unsigned int p = atomicAdd(cnt, 1u);
        if (p < CAP) { cand_s[p] = best; cand_i[p] = i; }
    }
}

// ---------------- single-wave helpers ----------------
__device__ __forceinline__ unsigned long long shflx64(unsigned long long v, int m) {
    int lo = __shfl_xor((int)(unsigned)(v & 0xFFFFFFFFull), m);
    int hi = __shfl_xor((int)(unsigned)(v >> 32), m);
    return ((unsigned long long)(unsigned)hi << 32) | (unsigned)lo;
}

// first-32 set bits (ascending index) of the 90000-bit mask; single wave, no barriers
__device__ int wave_first32(const unsigned long long* __restrict__ mask,
                            bool invert, int* __restrict__ outIdx, int lane) {
    const int NW = 1407;            // ceil(90000/64)
    const int WPT = 22;             // 64*22 = 1408 >= 1407
    unsigned long long mw[WPT];
    int cnt = 0;
#pragma unroll
    for (int u = 0; u < WPT; u++) {
        int w = lane * WPT + u;
        unsigned long long m = 0ull;
        if (w < NW) {
            m = mask[w];
            if (invert) m = ~m;
            if (w == NW - 1) m &= 0xFFFFull;    // anchors 89984..89999 only
        }
        mw[u] = m;
        cnt += __builtin_popcountll(m);
    }
    int inc = cnt;                  // inclusive prefix over lanes via shuffles
#pragma unroll
    for (int off = 1; off < 64; off <<= 1) {
        int v = __shfl_up(inc, off);
        if (lane >= off) inc += v;
    }
    int total = __shfl(inc, 63);
    int pref = inc - cnt;           // exclusive prefix
    if (pref < 32) {
#pragma unroll
        for (int u = 0; u < WPT; u++) {
            unsigned long long m = mw[u];
            int wbase = (lane * WPT + u) * 64;
            while (m && pref < 32) {
                int b = __builtin_ctzll(m);
                outIdx[pref++] = wbase + b;
                m &= m - 1;
            }
        }
    }
    return total;
}

// ---------------- tail: top-k selection + proposals + losses (one wave) ----------------
__global__ __launch_bounds__(64) void tail_kernel(const unsigned long long* __restrict__ negmask,
                                                  const unsigned long long* __restrict__ posmask,
                                                  const float* __restrict__ cand_s,
                                                  const int* __restrict__ cand_i,
                                                  const unsigned int* __restrict__ cnt,
                                                  const float* __restrict__ cpart,
                                                  const float* __restrict__ rpart,
                                                  const float* __restrict__ bcls,
                                                  const float* __restrict__ breg,
                                                  const int* __restrict__ aarg,
                                                  const float* __restrict__ gt,
                                                  const int* __restrict__ gtc,
                                                  float* __restrict__ out) {
    __shared__ unsigned long long keys[CAP + 32];
    __shared__ int sfill[32];
    __shared__ int spidx[32];
    __shared__ int snidx[32];
    int lane = threadIdx.x;

    // ---- build sort keys: (monotonic(score) << 32) | ~index  => max = (score desc, idx asc)
    int ncand = min((int)*cnt, CAP);
    for (int c = lane; c < ncand; c += 64) {
        unsigned u = __float_as_uint(cand_s[c]);
        u ^= (u & 0x80000000u) ? 0xFFFFFFFFu : 0x80000000u;
        keys[c] = ((unsigned long long)u << 32) | (0xFFFFFFFFu - (unsigned)cand_i[c]);
    }
    int ntot = ncand;
    if (ncand < 32) {               // jax top_k tie fill: first label!=1 anchors at value -1
        int tot = wave_first32(posmask, true, sfill, lane);
        int nfill = min(tot, 32);
        unsigned um1 = __float_as_uint(-1.0f) ^ 0xFFFFFFFFu;
        for (int k2 = lane; k2 < nfill; k2 += 64)
            keys[ncand + k2] = ((unsigned long long)um1 << 32) | (0xFFFFFFFFu - (unsigned)sfill[k2]);
        ntot += nfill;
    }

    // ---- 32 rounds of wave argmax; lane owns slots c == lane (mod 64)
    unsigned long long lk = 0ull; int ls = -1;
    for (int c = lane; c < ntot; c += 64) {
        unsigned long long k = keys[c];
        if (k > lk) { lk = k; ls = c; }
    }
    for (int s = 0; s < 32; s++) {
        unsigned long long mk = lk;
#pragma unroll
        for (int off = 1; off < 64; off <<= 1) {
            unsigned long long o = shflx64(mk, off);
            if (o > mk) mk = o;
        }
        if (lk == mk && mk != 0ull) {   // unique winner (keys embed unique indices)
            spidx[s] = (int)(0xFFFFFFFFu - (unsigned)(mk & 0xFFFFFFFFull));
            keys[ls] = 0ull;
            lk = 0ull; ls = -1;
            for (int c = lane; c < ntot; c += 64) {
                unsigned long long k = keys[c];
                if (k > lk) { lk = k; ls = c; }
            }
        }
    }

    // ---- negatives: first 32 label==0 anchors (ascending index)
    int totn = wave_first32(negmask, false, snidx, lane);
    if (lane == 0) {
        int nf = min(totn, 32);
        for (int s = nf; s < 32; s++) snidx[s] = s;   // degenerate fallback
    }

    // ---- finalize (same math as before) ----
    {
#pragma clang fp contract(off)
        const int PROP_OFF = 1 + 2560000;
        int t = lane;
        int n = (t < 32) ? spidx[t] : snidx[t - 32];
        int a = n % 9;
        int q = n / 9;
        int iy = q % 100;
        int ix = q / 100;
        int p = iy * 100 + ix;

        float l0 = bcls[a * 2 + 0], l1 = bcls[a * 2 + 1];
        for (int c = 0; c < 4; c++) {
            l0 += cpart[(c * 18 + a * 2 + 0) * 10000 + p];
            l1 += cpart[(c * 18 + a * 2 + 1) * 10000 + p];
        }
        float m = fmaxf(l0, l1);
        float lse = m + logf(expf(l0 - m) + expf(l1 - m));
        float logp = ((t < 32) ? l1 : l0) - lse;
        float cls_sum = logp;
#pragma unroll
        for (int off = 32; off > 0; off >>= 1) cls_sum += __shfl_down(cls_sum, off);

        float reg_sum = 0.f;
        if (t < 32) {
            float offv[4];
#pragma unroll
            for (int k = 0; k < 4; k++) {
                float v = breg[a * 4 + k];
                for (int c = 0; c < 4; c++) v += rpart[(c * 36 + a * 4 + k) * 10000 + p];
                offv[k] = v;
            }
            float x0, y0, x1, y1, aa;
            anchor_box(n, x0, y0, x1, y1, aa);
            float w = x1 - x0, h = y1 - y0;
            float cx = x0 + 0.5f * w, cy = y0 + 0.5f * h;
            float ncx = cx + offv[0] * w, ncy = cy + offv[1] * h;
            float nw = w * expf(offv[2]), nh = h * expf(offv[3]);
            out[PROP_OFF + t * 4 + 0] = ncx - nw * 0.5f;
            out[PROP_OFF + t * 4 + 1] = ncy - nh * 0.5f;
            out[PROP_OFF + t * 4 + 2] = ncx + nw * 0.5f;
            out[PROP_OFF + t * 4 + 3] = ncy + nh * 0.5f;

            int j = aarg[n];
            float g0 = gt[j * 4 + 0], g1 = gt[j * 4 + 1];
            float g2 = gt[j * 4 + 2], g3 = gt[j * 4 + 3];
            float gw = g2 - g0, gh = g3 - g1;
            float gcx = g0 + 0.5f * gw, gcy = g1 + 0.5f * gh;
            float tg[4];
            tg[0] = (gcx - cx) / w;
            tg[1] = (gcy - cy) / h;
            tg[2] = logf(gw / w);
            tg[3] = logf(gh / h);
#pragma unroll
            for (int k = 0; k < 4; k++) {
                float d = tg[k] - offv[k];
                float ad = fabsf(d);
                reg_sum += (ad < 1.f) ? 0.5f * d * d : ad - 0.5f;
            }
            out[PROP_OFF + 128 + t] = (float)n;
            out[PROP_OFF + 160 + t] = (float)gtc[j];
        }
#pragma unroll
        for (int off = 32; off > 0; off >>= 1) reg_sum += __shfl_down(reg_sum, off);
        if (t == 0) {
            float cls_loss = -(cls_sum / 64.f);
            float reg_loss = reg_sum / 128.f;
            out[0] = cls_loss + 5.f * reg_loss;
        }
    }
}

// ---------------- launch ----------------
extern "C" void kernel_launch(void* const* d_in, const int* in_sizes, int n_in,
                              void* d_out, int out_size, void* d_ws, size_t ws_size,
                              hipStream_t stream) {
    const float* img = (const float*)d_in[0];
    const float* gt  = (const float*)d_in[1];
    const int*   gtc = (const int*)d_in[2];
    const float* w1  = (const float*)d_in[3];
    const float* b1  = (const float*)d_in[4];
    const float* w2  = (const float*)d_in[5];
    const float* b2  = (const float*)d_in[6];
    const float* wr  = (const float*)d_in[7];
    const float* br  = (const float*)d_in[8];
    const float* wc  = (const float*)d_in[9];
    const float* bc  = (const float*)d_in[10];
    const float* wg  = (const float*)d_in[11];
    const float* bg  = (const float*)d_in[12];
    float* out = (float*)d_out;
    float* ws = (float*)d_ws;

    unsigned short* f1t  = (unsigned short*)(ws + OFF_F1T);
    unsigned short* fmt  = (unsigned short*)(ws + OFF_FMT);
    unsigned short* wa1  = (unsigned short*)(ws + OFF_WA1);
    unsigned short* w9_2 = (unsigned short*)(ws + OFF_W9_2);
    unsigned short* w9_3 = (unsigned short*)(ws + OFF_W9_3);
    float* hbuf  = ws + OFF_HBUF;
    float* cpart = ws + OFF_CPART;
    float* rpart = ws + OFF_RPART;
    float* wtc   = ws + OFF_WTC;
    float* wtg   = ws + OFF_WTG;
    int*   aarg  = (int*)(ws + OFF_AARG);
    unsigned long long* negm = (unsigned long long*)(ws + OFF_NEGM);
    unsigned long long* posm = (unsigned long long*)(ws + OFF_POSM);
    unsigned int* gtmax = (unsigned int*)(ws + OFF_GTMAX);
    unsigned int* cnt   = gtmax + 64;
    float* cands = ws + OFF_CANDS;
    int*   candi = (int*)(ws + OFF_CANDI);
    float* fm    = out + 1;   // fm lives directly in the output buffer (f32)

    setup_kernel<<<dim3(3385), dim3(256), 0, stream>>>(wc, wtc, wg, wtg, w1, wa1,
                                                       w2, w9_2, wr, w9_3,
                                                       (unsigned int*)f1t, (unsigned int*)fmt, gtmax);

    conv1_mfma<<<dim3(7, 400), dim3(256), 0, stream>>>(img, wa1, b1, f1t);
    conv_gemm<64, 402, 4, true><<<dim3(4, 100), dim3(256), 0, stream>>>(f1t, w9_2, b2, fm, fmt);
    conv_gemm<256, 102, 1, false><<<dim3(4, 100), dim3(256), 0, stream>>>(fmt, w9_3, br, hbuf, nullptr);
    head_kernel<<<dim3(157, 4), dim3(64), 0, stream>>>(hbuf, wtc, wtg, cpart, rpart);

    iou_pass1<<<dim3(352), dim3(256), 0, stream>>>(gt, aarg, gtmax);
    iou_pass2<<<dim3(352), dim3(256), 0, stream>>>(gt, gtmax, negm, posm, cands, candi, cnt);
    tail_kernel<<<dim3(1), dim3(64), 0, stream>>>(negm, posm, cands, candi, cnt,
                                                  cpart, rpart, bc, bg, aarg, gt, gtc, out);
}